// Round 2
// baseline (304.296 us; speedup 1.0000x reference)
//
#include <hip/hip_runtime.h>

#define HEADS 64
#define SEQ 2048
#define DIM 64
#define BR 128   // q rows per block (32 per wave)
#define BC 64    // keys per tile

typedef __attribute__((ext_vector_type(4))) float f32x4;
typedef __attribute__((ext_vector_type(8))) short s16x8;
typedef __attribute__((ext_vector_type(4))) unsigned int u32x4;

__device__ __forceinline__ unsigned short f2bf(float f) {
  unsigned u = __builtin_bit_cast(unsigned, f);
  return (unsigned short)((u + 0x8000u) >> 16);
}
// pack two fp32 -> two bf16 (round-half-up) in one v_perm
__device__ __forceinline__ unsigned pack2(float lo, float hi) {
  unsigned a = __builtin_bit_cast(unsigned, hi) + 0x8000u;
  unsigned b = __builtin_bit_cast(unsigned, lo) + 0x8000u;
  return __builtin_amdgcn_perm(a, b, 0x07060302u);
}

// Aliasing-safe LDS access (memcpy lowers to single ds_read_b128 / ds_write_b64)
__device__ __forceinline__ s16x8 lds_read8(const unsigned short* p) {
  s16x8 r;
  __builtin_memcpy(&r, p, 16);
  return r;
}
__device__ __forceinline__ void lds_write4(unsigned short* p, unsigned lo, unsigned hi) {
  uint2 v;
  v.x = lo;
  v.y = hi;
  __builtin_memcpy(p, &v, 8);
}

__global__ __launch_bounds__(256, 2) void fattn_kernel(
    const float* __restrict__ Qg, const float* __restrict__ Kg,
    const float* __restrict__ Vg, float* __restrict__ Og) {
  // K tile:  [key][d ^ 8*(key&7)]   (XOR swizzle, granularity 8 -> b128 reads stay contiguous)
  // Vt tile: [d][key ^ 8*(d&7)]
  // Pt tile (per wave): [qrow][key ^ 8*(qrow&7)]
  __shared__ __align__(16) unsigned short klds[BC * DIM];
  __shared__ __align__(16) unsigned short vtlds[DIM * BC];
  __shared__ __align__(16) unsigned short ptlds[4][32 * BC];

  const int tid = threadIdx.x;
  const int w = tid >> 6;
  const int lane = tid & 63;
  const int q = lane >> 4;   // quad
  const int c = lane & 15;   // m/n index within 16
  const int head = blockIdx.x & 63;   // head h -> XCD h%8 (L2 affinity for K/V re-reads)
  const int qblk = blockIdx.x >> 6;
  const int hbase = head * (SEQ * DIM);
  const int qbase = qblk * BR + w * 32;

  const float qscale = 0.18033688011112042f;  // log2(e) / sqrt(64), folded into Q

  // Q fragments (B operand of S^T = K.Q^T): lane holds Q[qrow = c + 16*n][d = q*8+j + 32*kc]
  s16x8 qf[2][2];
#pragma unroll
  for (int n = 0; n < 2; ++n) {
    const float* qp = Qg + hbase + (qbase + n * 16 + c) * DIM + q * 8;
#pragma unroll
    for (int kc = 0; kc < 2; ++kc) {
      float4 x = *(const float4*)(qp + kc * 32);
      float4 y = *(const float4*)(qp + kc * 32 + 4);
      u32x4 t = {pack2(x.x * qscale, x.y * qscale),
                 pack2(x.z * qscale, x.w * qscale),
                 pack2(y.x * qscale, y.y * qscale),
                 pack2(y.z * qscale, y.w * qscale)};
      qf[n][kc] = __builtin_bit_cast(s16x8, t);
    }
  }

  const f32x4 vzero = {0.f, 0.f, 0.f, 0.f};
  float mrun[2] = {-1e30f, -1e30f};
  float lrun[2] = {0.f, 0.f};
  f32x4 oacc[4][2];
#pragma unroll
  for (int mt = 0; mt < 4; ++mt) {
    oacc[mt][0] = vzero;
    oacc[mt][1] = vzero;
  }

  for (int kb = 0; kb < SEQ / BC; ++kb) {
    __syncthreads();  // A: previous-iter readers of klds/vtlds are done
    const int kvbase = hbase + kb * BC * DIM;
    // ---- stage K tile (row-major, swizzled): coalesced float4 reads, b64 LDS writes
#pragma unroll
    for (int it = 0; it < 4; ++it) {
      int key = (tid >> 4) + 16 * it;
      int d0 = (tid & 15) * 4;
      float4 kv = *(const float4*)(Kg + kvbase + key * DIM + d0);
      lds_write4(&klds[key * DIM + (d0 ^ ((key & 7) * 8))],
                 pack2(kv.x, kv.y), pack2(kv.z, kv.w));
    }
    // ---- stage V transposed (64B-segment reads, scalar swizzled writes)
#pragma unroll
    for (int it = 0; it < 4; ++it) {
      int key = (tid & 15) + 16 * it;
      int d0 = (tid >> 4) * 4;
      float4 vv = *(const float4*)(Vg + kvbase + key * DIM + d0);
      vtlds[(d0 + 0) * BC + (key ^ (((d0 + 0) & 7) * 8))] = f2bf(vv.x);
      vtlds[(d0 + 1) * BC + (key ^ (((d0 + 1) & 7) * 8))] = f2bf(vv.y);
      vtlds[(d0 + 2) * BC + (key ^ (((d0 + 2) & 7) * 8))] = f2bf(vv.z);
      vtlds[(d0 + 3) * BC + (key ^ (((d0 + 3) & 7) * 8))] = f2bf(vv.w);
    }
    __syncthreads();  // B: staging visible to all waves

    // ---- S^T = K . Q^T : D[key = 4q+r+16kt][qrow = c]
    f32x4 st[4][2];
#pragma unroll
    for (int kt = 0; kt < 4; ++kt) {
      st[kt][0] = vzero;
      st[kt][1] = vzero;
    }
#pragma unroll
    for (int kc = 0; kc < 2; ++kc) {
#pragma unroll
      for (int kt = 0; kt < 4; ++kt) {
        s16x8 kf = lds_read8(&klds[(c + 16 * kt) * DIM +
                                   ((kc * 32 + q * 8) ^ ((c & 7) * 8))]);
        st[kt][0] = __builtin_amdgcn_mfma_f32_16x16x32_bf16(kf, qf[0][kc], st[kt][0], 0, 0, 0);
        st[kt][1] = __builtin_amdgcn_mfma_f32_16x16x32_bf16(kf, qf[1][kc], st[kt][1], 0, 0, 0);
      }
    }

    // ---- online softmax per q-row (= per lane column) + write P^T to LDS
#pragma unroll
    for (int n = 0; n < 2; ++n) {
      float smax = st[0][n][0];
#pragma unroll
      for (int kt = 0; kt < 4; ++kt)
#pragma unroll
        for (int r = 0; r < 4; ++r) smax = fmaxf(smax, st[kt][n][r]);
      smax = fmaxf(smax, __shfl_xor(smax, 16));
      smax = fmaxf(smax, __shfl_xor(smax, 32));
      float mnew = fmaxf(mrun[n], smax);
      float alpha = exp2f(mrun[n] - mnew);
      mrun[n] = mnew;
      float rsum = 0.f;
#pragma unroll
      for (int kt = 0; kt < 4; ++kt)
#pragma unroll
        for (int r = 0; r < 4; ++r) {
          float p = exp2f(st[kt][n][r] - mnew);
          st[kt][n][r] = p;
          rsum += p;
        }
      rsum += __shfl_xor(rsum, 16);
      rsum += __shfl_xor(rsum, 32);
      lrun[n] = lrun[n] * alpha + rsum;
#pragma unroll
      for (int mt = 0; mt < 4; ++mt) oacc[mt][n] *= alpha;
      // C-layout gives 4 consecutive keys per reg quad -> b64 writes
      int row = c + 16 * n;
#pragma unroll
      for (int kt = 0; kt < 4; ++kt) {
        lds_write4(&ptlds[w][row * BC + ((16 * kt + 4 * q) ^ ((c & 7) * 8))],
                   pack2(st[kt][n][0], st[kt][n][1]),
                   pack2(st[kt][n][2], st[kt][n][3]));
      }
    }

    // C: architecturally drain the P^T ds_writes (lgkmcnt(0)+s_barrier) before
    // the cross-lane ds_read_b128 of P^T. Same-wave write->read through LDS at
    // a different lane mapping is NOT ordered without this — R1's replay race.
    __syncthreads();

    // ---- O^T += V^T . P^T : D[d = 4q+r+16mt][qrow = c]
#pragma unroll
    for (int kc = 0; kc < 2; ++kc) {
      s16x8 pf0 = lds_read8(&ptlds[w][c * BC + ((kc * 32 + q * 8) ^ ((c & 7) * 8))]);
      s16x8 pf1 = lds_read8(&ptlds[w][(c + 16) * BC + ((kc * 32 + q * 8) ^ ((c & 7) * 8))]);
#pragma unroll
      for (int mt = 0; mt < 4; ++mt) {
        s16x8 vf = lds_read8(&vtlds[(c + 16 * mt) * BC +
                                    ((kc * 32 + q * 8) ^ ((c & 7) * 8))]);
        oacc[mt][0] = __builtin_amdgcn_mfma_f32_16x16x32_bf16(vf, pf0, oacc[mt][0], 0, 0, 0);
        oacc[mt][1] = __builtin_amdgcn_mfma_f32_16x16x32_bf16(vf, pf1, oacc[mt][1], 0, 0, 0);
      }
    }
  }

  // ---- epilogue: O = O^T / l, 4 consecutive d per lane -> float4 stores
#pragma unroll
  for (int n = 0; n < 2; ++n) {
    float inv = 1.0f / lrun[n];
    int row = qbase + 16 * n + c;
#pragma unroll
    for (int mt = 0; mt < 4; ++mt) {
      f32x4 r = oacc[mt][n] * inv;
      *(f32x4*)(Og + hbase + row * DIM + 16 * mt + 4 * q) = r;
    }
  }
}

extern "C" void kernel_launch(void* const* d_in, const int* in_sizes, int n_in,
                              void* d_out, int out_size, void* d_ws, size_t ws_size,
                              hipStream_t stream) {
  const float* Q = (const float*)d_in[0];
  const float* K = (const float*)d_in[1];
  const float* V = (const float*)d_in[2];
  float* O = (float*)d_out;
  dim3 grid(HEADS * (SEQ / BR));
  dim3 block(256);
  hipLaunchKernelGGL(fattn_kernel, grid, block, 0, stream, Q, K, V, O);
}